// Round 3
// baseline (461.981 us; speedup 1.0000x reference)
//
#include <hip/hip_runtime.h>
#include <hip/hip_bf16.h>
#include <math.h>

typedef __attribute__((ext_vector_type(8))) short short8;
typedef __attribute__((ext_vector_type(4))) float floatx4;
typedef __hip_bfloat16 bf16;

#define LDSP 40  // padded LDS row stride (bf16 elems): 80B rows -> 2-way (free) bank aliasing

__device__ __forceinline__ float sigmoidf_(float v) { return 1.f / (1.f + __expf(-v)); }

// ---------------------------------------------------------------------------
// Shared 64x64-tile bf16 MFMA GEMM core. 256 threads = 4 waves (2x2), each
// wave owns a 32x32 output tile = 2x2 fragments of v_mfma_f32_16x16x32_bf16.
// B is consumed transposed (Bt rows = output channels) so both A and B
// fragments are contiguous bf16x8 loads (k-consecutive per lane).
// DUAL: K-loop spans two (A,Bt) pairs.
// ---------------------------------------------------------------------------
template<bool DUAL>
__device__ __forceinline__ void gemm_core(
    const bf16* A0p, const bf16* A1p, int lda,
    const bf16* B0, const bf16* B1, int ldb,
    int ksteps, floatx4 acc[2][2], bf16* As, bf16* Bs)
{
  const int tid  = threadIdx.x;
  const int lane = tid & 63;
  const int wave = tid >> 6;
  const int wm = wave >> 1, wn = wave & 1;
  const int srow = tid >> 2, sseg = tid & 3;   // staging: 64 rows x 4 segs of 8 elems
  const size_t m0 = (size_t)blockIdx.x * 64;
  const size_t n0 = (size_t)blockIdx.y * 64;
  const int half = DUAL ? (ksteps >> 1) : ksteps;
  const int fr = lane & 15, kb = lane >> 4;

  #pragma unroll
  for (int i = 0; i < 2; ++i)
    #pragma unroll
    for (int j = 0; j < 2; ++j) acc[i][j] = {0.f, 0.f, 0.f, 0.f};

  for (int kt = 0; kt < ksteps; ++kt) {
    const bool second = DUAL && (kt >= half);
    const bf16* Ap = second ? A1p : A0p;
    const bf16* Bp = second ? B1 : B0;
    const int kbase = (second ? (kt - half) : kt) * 32 + sseg * 8;

    *(short8*)&As[srow * LDSP + sseg * 8] =
        *(const short8*)(Ap + (m0 + srow) * (size_t)lda + kbase);
    *(short8*)&Bs[srow * LDSP + sseg * 8] =
        *(const short8*)(Bp + (n0 + srow) * (size_t)ldb + kbase);
    __syncthreads();

    short8 a0 = *(const short8*)&As[(wm * 32 + fr)      * LDSP + kb * 8];
    short8 a1 = *(const short8*)&As[(wm * 32 + 16 + fr) * LDSP + kb * 8];
    short8 b0 = *(const short8*)&Bs[(wn * 32 + fr)      * LDSP + kb * 8];
    short8 b1 = *(const short8*)&Bs[(wn * 32 + 16 + fr) * LDSP + kb * 8];
    acc[0][0] = __builtin_amdgcn_mfma_f32_16x16x32_bf16(a0, b0, acc[0][0], 0, 0, 0);
    acc[0][1] = __builtin_amdgcn_mfma_f32_16x16x32_bf16(a0, b1, acc[0][1], 0, 0, 0);
    acc[1][0] = __builtin_amdgcn_mfma_f32_16x16x32_bf16(a1, b0, acc[1][0], 0, 0, 0);
    acc[1][1] = __builtin_amdgcn_mfma_f32_16x16x32_bf16(a1, b1, acc[1][1], 0, 0, 0);
    __syncthreads();
  }
}

// C/D fragment element (verified m89/m91): col = lane&15, row = (lane>>4)*4 + reg
#define EPI_PREAMBLE \
  const int tid = threadIdx.x, lane = tid & 63, wave = tid >> 6; \
  const int wm = wave >> 1, wn = wave & 1; \
  const int m0 = blockIdx.x * 64, n0 = blockIdx.y * 64; \
  const int rq = lane >> 4, col = lane & 15; \
  (void)m0;

// ---- weight transpose+cast: dst[c][r] = src[r][c], zero-pad r in [rows,dld)
__global__ void k_transpose(const float* __restrict__ src, bf16* __restrict__ dst,
                            int rows, int cols, int dld) {
  int idx = blockIdx.x * 256 + threadIdx.x;
  if (idx >= cols * dld) return;
  int c = idx / dld, r = idx - c * dld;
  float v = (r < rows) ? src[(size_t)r * cols + c] : 0.f;
  dst[idx] = __float2bfloat16(v);
}

// ---------------------------------------------------------------------------
// GEMM1 (wide): h = tanh(x @ Wx + bx) -> scatter to center/neigh. Each block
// computes 64 rows x ALL 256 cols so x (167 MB fp32) is read exactly once.
// fp32 x is converted to bf16 during LDS staging; K padded 300->320 via WxT.
// LDS: A-slice 64x32 (5.1KB) + B-slice 256x32 (20.5KB).
// ---------------------------------------------------------------------------
__global__ __launch_bounds__(256) void k_gemm1_wide(
    const float* __restrict__ x, const bf16* __restrict__ WxT,
    const float* __restrict__ bx, bf16* __restrict__ center, bf16* __restrict__ neigh) {
  __shared__ bf16 As[64 * LDSP], Bs[256 * LDSP];
  const int tid  = threadIdx.x;
  const int lane = tid & 63;
  const int wave = tid >> 6;
  const int wm = wave >> 1, wn = wave & 1;
  const int srow = tid >> 2, sseg = tid & 3;
  const size_t m0 = (size_t)blockIdx.x * 64;
  const int fr = lane & 15, kb = lane >> 4;

  floatx4 acc[4][2][2];
  #pragma unroll
  for (int nt = 0; nt < 4; ++nt)
    #pragma unroll
    for (int i = 0; i < 2; ++i)
      #pragma unroll
      for (int j = 0; j < 2; ++j) acc[nt][i][j] = {0.f, 0.f, 0.f, 0.f};

  for (int kt = 0; kt < 10; ++kt) {
    const int kbase = kt * 32 + sseg * 8;
    // stage A (fp32 -> bf16), zero-pad past K=300
    {
      const float* Af = x + (m0 + srow) * (size_t)300 + kbase;
      union { bf16 b[8]; short8 v; } u;
      if (kbase + 8 <= 300) {
        float4 f0 = *(const float4*)Af;
        float4 f1 = *(const float4*)(Af + 4);
        u.b[0] = __float2bfloat16(f0.x); u.b[1] = __float2bfloat16(f0.y);
        u.b[2] = __float2bfloat16(f0.z); u.b[3] = __float2bfloat16(f0.w);
        u.b[4] = __float2bfloat16(f1.x); u.b[5] = __float2bfloat16(f1.y);
        u.b[6] = __float2bfloat16(f1.z); u.b[7] = __float2bfloat16(f1.w);
      } else {
        #pragma unroll
        for (int j = 0; j < 8; ++j)
          u.b[j] = __float2bfloat16((kbase + j < 300) ? Af[j] : 0.f);
      }
      *(short8*)&As[srow * LDSP + sseg * 8] = u.v;
    }
    // stage B: all 256 weight rows (4 per thread)
    #pragma unroll
    for (int it = 0; it < 4; ++it) {
      const int brow = it * 64 + srow;
      *(short8*)&Bs[brow * LDSP + sseg * 8] =
          *(const short8*)(WxT + (size_t)brow * 320 + kbase);
    }
    __syncthreads();

    short8 a0 = *(const short8*)&As[(wm * 32 + fr)      * LDSP + kb * 8];
    short8 a1 = *(const short8*)&As[(wm * 32 + 16 + fr) * LDSP + kb * 8];
    #pragma unroll
    for (int nt = 0; nt < 4; ++nt) {
      short8 b0 = *(const short8*)&Bs[(nt * 64 + wn * 32 + fr)      * LDSP + kb * 8];
      short8 b1 = *(const short8*)&Bs[(nt * 64 + wn * 32 + 16 + fr) * LDSP + kb * 8];
      acc[nt][0][0] = __builtin_amdgcn_mfma_f32_16x16x32_bf16(a0, b0, acc[nt][0][0], 0, 0, 0);
      acc[nt][0][1] = __builtin_amdgcn_mfma_f32_16x16x32_bf16(a0, b1, acc[nt][0][1], 0, 0, 0);
      acc[nt][1][0] = __builtin_amdgcn_mfma_f32_16x16x32_bf16(a1, b0, acc[nt][1][0], 0, 0, 0);
      acc[nt][1][1] = __builtin_amdgcn_mfma_f32_16x16x32_bf16(a1, b1, acc[nt][1][1], 0, 0, 0);
    }
    __syncthreads();
  }

  const int rq = lane >> 4, col = lane & 15;
  #pragma unroll
  for (int nt = 0; nt < 4; ++nt)
    #pragma unroll
    for (int i = 0; i < 2; ++i)
      #pragma unroll
      for (int j = 0; j < 2; ++j) {
        int gc = nt * 64 + wn * 32 + j * 16 + col;
        float bias = bx[gc];
        #pragma unroll
        for (int r = 0; r < 4; ++r) {
          int gm = (int)m0 + wm * 32 + i * 16 + rq * 4 + r;
          float v = tanhf(acc[nt][i][j][r] + bias);
          int node = gm / 17, slot = gm - node * 17;
          bf16 bv = __float2bfloat16(v);
          if (slot == 0) center[(size_t)node * 256 + gc] = bv;
          else           neigh[((size_t)node * 16 + (slot - 1)) * 256 + gc] = bv;
        }
      }
}

// ---- small GEMM: out = act(A @ Bt^T + bias). ACT 0: none->f32, 1: sigmoid->bf16
template<int ACT>
__global__ __launch_bounds__(256) void k_gemm_simple(
    const bf16* __restrict__ A, const bf16* __restrict__ Bt,
    const float* __restrict__ bias, void* __restrict__ outp) {
  __shared__ bf16 As[64 * LDSP], Bs[64 * LDSP];
  floatx4 acc[2][2];
  gemm_core<false>(A, nullptr, 256, Bt, nullptr, 256, 8, acc, As, Bs);
  EPI_PREAMBLE
  #pragma unroll
  for (int i = 0; i < 2; ++i)
    #pragma unroll
    for (int j = 0; j < 2; ++j) {
      int gc = n0 + wn * 32 + j * 16 + col;
      float b = bias[gc];
      #pragma unroll
      for (int r = 0; r < 4; ++r) {
        int gm = m0 + wm * 32 + i * 16 + rq * 4 + r;
        float v = acc[i][j][r] + b;
        if (ACT == 1) ((bf16*)outp)[(size_t)gm * 256 + gc] = __float2bfloat16(sigmoidf_(v));
        else          ((float*)outp)[(size_t)gm * 256 + gc] = v;
      }
    }
}

// ---- neigh @ Uh with fused masked softmax over K=16 and con reduction.
// Each 16x16 C fragment = one node (16 neighbor rows) x 16 channels; the
// softmax axis lives on the fragment's row axis: 4 regs x lanes {c,c+16,c+32,c+48}.
__global__ __launch_bounds__(256) void k_gemm_attn(
    const bf16* __restrict__ neigh, const bf16* __restrict__ UhT,
    const float* __restrict__ bu, const float* __restrict__ Ct,
    const int* __restrict__ cnts, bf16* __restrict__ con) {
  __shared__ bf16 As[64 * LDSP], Bs[64 * LDSP];
  floatx4 acc[2][2];
  gemm_core<false>(neigh, nullptr, 256, UhT, nullptr, 256, 8, acc, As, Bs);
  EPI_PREAMBLE
  #pragma unroll
  for (int i = 0; i < 2; ++i) {
    const int node = blockIdx.x * 4 + wm * 2 + i;
    const int cnt = cnts[node];
    #pragma unroll
    for (int j = 0; j < 2; ++j) {
      const int gc = n0 + wn * 32 + j * 16 + col;
      const float add = bu[gc] + Ct[(size_t)node * 256 + gc];
      float t[4];
      float mx = -1e30f;
      #pragma unroll
      for (int r = 0; r < 4; ++r) {
        int k = rq * 4 + r;
        t[r] = sigmoidf_(acc[i][j][r] + add);
        if (k < cnt) mx = fmaxf(mx, t[r]);
      }
      mx = fmaxf(mx, __shfl_xor(mx, 16, 64));
      mx = fmaxf(mx, __shfl_xor(mx, 32, 64));
      float ps = 0.f, cs = 0.f;
      #pragma unroll
      for (int r = 0; r < 4; ++r) {
        int k = rq * 4 + r;
        float p = (k < cnt) ? __expf(t[r] - mx) : 0.f;
        ps += p;
        cs += p * __bfloat162float(neigh[((size_t)node * 16 + k) * 256 + gc]);
      }
      ps += __shfl_xor(ps, 16, 64); ps += __shfl_xor(ps, 32, 64);
      cs += __shfl_xor(cs, 16, 64); cs += __shfl_xor(cs, 32, 64);
      if (rq == 0) con[(size_t)node * 256 + gc] = __float2bfloat16(cs / ps);
    }
  }
}

// ---- gate: acc = center@Wg + con@Ug (K=512 dual loop); z = g*center+(1-g)*con
__global__ __launch_bounds__(256) void k_gemm_gate(
    const bf16* __restrict__ center, const bf16* __restrict__ con,
    const bf16* __restrict__ WgT, const bf16* __restrict__ UgT,
    const float* __restrict__ bg, const float* __restrict__ bug,
    bf16* __restrict__ zb, float* __restrict__ zf) {
  __shared__ bf16 As[64 * LDSP], Bs[64 * LDSP];
  floatx4 acc[2][2];
  gemm_core<true>(center, con, 256, WgT, UgT, 256, 16, acc, As, Bs);
  EPI_PREAMBLE
  #pragma unroll
  for (int i = 0; i < 2; ++i)
    #pragma unroll
    for (int j = 0; j < 2; ++j) {
      int gc = n0 + wn * 32 + j * 16 + col;
      float b2 = bg[gc] + bug[gc];
      #pragma unroll
      for (int r = 0; r < 4; ++r) {
        int gm = m0 + wm * 32 + i * 16 + rq * 4 + r;
        float g  = sigmoidf_(acc[i][j][r] + b2);
        float cv = __bfloat162float(center[(size_t)gm * 256 + gc]);
        float ov = __bfloat162float(con[(size_t)gm * 256 + gc]);
        float zv = g * cv + (1.f - g) * ov;
        zb[(size_t)gm * 256 + gc] = __float2bfloat16(zv);
        zf[(size_t)gm * 256 + gc] = zv;
      }
    }
}

// ---- softmax over N=128 (axis=1) fused with sent = sum(av*z): one block per
// batch, thread = channel, online softmax, fully coalesced.
__global__ __launch_bounds__(256) void k_rowsoftmax(
    const float* __restrict__ L, const float* __restrict__ zf, float* __restrict__ sent) {
  const int b = blockIdx.x, c = threadIdx.x;
  float m = -1e30f, s = 0.f, acc = 0.f;
  for (int n = 0; n < 128; ++n) {
    size_t idx = ((size_t)b * 128 + n) * 256 + c;
    float v = L[idx];
    if (v > m) { float sc = __expf(m - v); s *= sc; acc *= sc; m = v; }
    float p = __expf(v - m);
    s += p;
    acc += p * zf[idx];
  }
  sent[b * 256 + c] = acc / s;
}

// ---- final: log_softmax(sent @ Wc + bc). One wave per batch row.
__global__ __launch_bounds__(64) void k_final(
    const float* __restrict__ sent, const float* __restrict__ Wc,
    const float* __restrict__ bc, float* __restrict__ out) {
  const int b = blockIdx.x, l = threadIdx.x;
  float part[5] = {0.f, 0.f, 0.f, 0.f, 0.f};
  #pragma unroll
  for (int u = 0; u < 4; ++u) {
    int c = l * 4 + u;
    float sv = sent[b * 256 + c];
    #pragma unroll
    for (int j = 0; j < 5; ++j) part[j] += sv * Wc[c * 5 + j];
  }
  #pragma unroll
  for (int j = 0; j < 5; ++j)
    for (int d = 1; d < 64; d <<= 1) part[j] += __shfl_xor(part[j], d, 64);
  if (l == 0) {
    float lg[5], mx = -1e30f;
    #pragma unroll
    for (int j = 0; j < 5; ++j) { lg[j] = part[j] + bc[j]; mx = fmaxf(mx, lg[j]); }
    float ss = 0.f;
    #pragma unroll
    for (int j = 0; j < 5; ++j) ss += __expf(lg[j] - mx);
    float lse = logf(ss) + mx;
    #pragma unroll
    for (int j = 0; j < 5; ++j) out[b * 5 + j] = lg[j] - lse;
  }
}

extern "C" void kernel_launch(void* const* d_in, const int* in_sizes, int n_in,
                              void* d_out, int out_size, void* d_ws, size_t ws_size,
                              hipStream_t stream) {
  const float* x    = (const float*)d_in[0];
  const int*   cnts = (const int*)d_in[1];
  const float* Wx_w = (const float*)d_in[2];  const float* Wx_b = (const float*)d_in[3];
  const float* Wh_w = (const float*)d_in[4];  const float* Wh_b = (const float*)d_in[5];
  const float* Uh_w = (const float*)d_in[6];  const float* Uh_b = (const float*)d_in[7];
  const float* Wg_w = (const float*)d_in[8];  const float* Wg_b = (const float*)d_in[9];
  const float* Ug_w = (const float*)d_in[10]; const float* Ug_b = (const float*)d_in[11];
  const float* Wa_w = (const float*)d_in[12]; const float* Wa_b = (const float*)d_in[13];
  const float* V_w  = (const float*)d_in[14]; const float* V_b  = (const float*)d_in[15];
  const float* Wc_w = (const float*)d_in[16]; const float* Wc_b = (const float*)d_in[17];
  float* out = (float*)d_out;
  (void)in_sizes; (void)n_in; (void)out_size;

  char* ws = (char*)d_ws;
  size_t off = 0;
  auto alloc = [&](size_t bytes) -> char* {
    char* p = ws + off; off += (bytes + 255) & ~(size_t)255; return p;
  };
  bf16* WxT    = (bf16*)alloc(256 * 320 * sizeof(bf16)); // zero-padded K 300->320
  bf16* WhT    = (bf16*)alloc(256 * 256 * sizeof(bf16));
  bf16* UhT    = (bf16*)alloc(256 * 256 * sizeof(bf16));
  bf16* WgT    = (bf16*)alloc(256 * 256 * sizeof(bf16));
  bf16* UgT    = (bf16*)alloc(256 * 256 * sizeof(bf16));
  bf16* WaT    = (bf16*)alloc(256 * 256 * sizeof(bf16));
  bf16* VT     = (bf16*)alloc(256 * 256 * sizeof(bf16));
  bf16* center = (bf16*)alloc((size_t)8192 * 256 * 2);
  bf16* neigh  = (bf16*)alloc((size_t)131072 * 256 * 2);
  float* Ct    = (float*)alloc((size_t)8192 * 256 * 4);   // reused as L after attn
  bf16* con    = (bf16*)alloc((size_t)8192 * 256 * 2);
  bf16* zb     = (bf16*)alloc((size_t)8192 * 256 * 2);
  float* zf    = (float*)alloc((size_t)8192 * 256 * 4);
  bf16* S      = (bf16*)alloc((size_t)8192 * 256 * 2);
  float* sent  = (float*)alloc((size_t)64 * 256 * 4);
  float* L     = Ct;  // Ct is dead after k_gemm_attn; alias saves 8 MB
  if (off > ws_size) return;  // fail loudly (wrong output) rather than corrupt

  // weight prep (independent; serialized on stream is fine, they're tiny)
  k_transpose<<<dim3(320), 256, 0, stream>>>(Wx_w, WxT, 300, 256, 320);
  k_transpose<<<dim3(256), 256, 0, stream>>>(Wh_w, WhT, 256, 256, 256);
  k_transpose<<<dim3(256), 256, 0, stream>>>(Uh_w, UhT, 256, 256, 256);
  k_transpose<<<dim3(256), 256, 0, stream>>>(Wg_w, WgT, 256, 256, 256);
  k_transpose<<<dim3(256), 256, 0, stream>>>(Ug_w, UgT, 256, 256, 256);
  k_transpose<<<dim3(256), 256, 0, stream>>>(Wa_w, WaT, 256, 256, 256);
  k_transpose<<<dim3(256), 256, 0, stream>>>(V_w,  VT,  256, 256, 256);

  // h = tanh(x@Wx+b) -> center(8192x256) + neigh(131072x256), bf16; x read ONCE
  k_gemm1_wide<<<dim3(2176), 256, 0, stream>>>(x, WxT, Wx_b, center, neigh);
  // Ct = center@Wh + bh (fp32)
  k_gemm_simple<0><<<dim3(128, 4), 256, 0, stream>>>(center, WhT, Wh_b, Ct);
  // con = sum_k softmax_k(sigmoid(Ct + neigh@Uh + bu), mask) * neigh
  k_gemm_attn<<<dim3(2048, 4), 256, 0, stream>>>(neigh, UhT, Uh_b, Ct, cnts, con);
  // z = g*center + (1-g)*con, g = sigmoid(center@Wg + con@Ug + bg + bug)
  k_gemm_gate<<<dim3(128, 4), 256, 0, stream>>>(center, con, WgT, UgT, Wg_b, Ug_b, zb, zf);
  // S = sigmoid(z@Wa + ba)
  k_gemm_simple<1><<<dim3(128, 4), 256, 0, stream>>>(zb, WaT, Wa_b, S);
  // L = S@V + bv (fp32, aliases Ct)
  k_gemm_simple<0><<<dim3(128, 4), 256, 0, stream>>>(S, VT, V_b, L);
  // sent = sum_n softmax_n(L) * z
  k_rowsoftmax<<<dim3(64), 256, 0, stream>>>(L, zf, sent);
  // out = log_softmax(sent@Wc + bc)
  k_final<<<dim3(64), 64, 0, stream>>>(sent, Wc_w, Wc_b, out);
}